// Round 1
// baseline (7834.588 us; speedup 1.0000x reference)
//
#include <hip/hip_runtime.h>
#include <math.h>

#define BATCH 512
#define NG 16
#define GSZ 32
#define H 128
#define E 64
#define PRE 512
#define BOT 1024
#define MLPD 1024
#define SEQ 12

// ---------------------------------------------------------------- init
__global__ void init_kernel(const float* __restrict__ hh, const float* __restrict__ ch,
                            const float* __restrict__ last_pos,
                            float* __restrict__ hbuf, float* __restrict__ cbuf,
                            float* __restrict__ pos, float* __restrict__ loss) {
    int idx = blockIdx.x * blockDim.x + threadIdx.x;
    if (idx < BATCH * H) { hbuf[idx] = hh[idx]; cbuf[idx] = ch[idx]; }
    if (idx < BATCH * 2) { pos[idx] = last_pos[idx]; }
    if (idx == 0) *loss = 0.0f;
}

// ---------------------------------------------------------------- LSTM cell (+emb, +rel_pos, +loss)
__global__ __launch_bounds__(128) void lstm_step(
    const float* __restrict__ relin, const float* __restrict__ gt,
    const float* __restrict__ Wse, const float* __restrict__ bse,
    const float* __restrict__ Wih, const float* __restrict__ Whh,
    const float* __restrict__ bih, const float* __restrict__ bhh,
    const float* __restrict__ Wpos, const float* __restrict__ bpos,
    float* __restrict__ hbuf, float* __restrict__ cbuf, float* __restrict__ hl,
    float* __restrict__ pos, float* __restrict__ traj, float* __restrict__ loss)
{
    int b = blockIdx.x, tid = threadIdx.x;
    __shared__ __align__(16) float xe[E];
    __shared__ __align__(16) float hp[H];
    __shared__ __align__(16) float hn[H];
    if (tid < E) {
        float rx = relin[b * 2 + 0], ry = relin[b * 2 + 1];
        xe[tid] = bse[tid] + Wse[tid * 2 + 0] * rx + Wse[tid * 2 + 1] * ry;
    }
    hp[tid] = hbuf[b * H + tid];
    __syncthreads();

    float g4[4];
    const float4* xev = (const float4*)xe;
    const float4* hpv = (const float4*)hp;
#pragma unroll
    for (int q = 0; q < 4; q++) {
        int row = q * H + tid;
        float acc = bih[row] + bhh[row];
        const float4* wi = (const float4*)(Wih + row * E);
#pragma unroll 4
        for (int k = 0; k < E / 4; k++) {
            float4 w = wi[k], x = xev[k];
            acc += w.x * x.x + w.y * x.y + w.z * x.z + w.w * x.w;
        }
        const float4* wh = (const float4*)(Whh + row * H);
#pragma unroll 4
        for (int k = 0; k < H / 4; k++) {
            float4 w = wh[k], x = hpv[k];
            acc += w.x * x.x + w.y * x.y + w.z * x.z + w.w * x.w;
        }
        g4[q] = acc;
    }
    float ig = 1.0f / (1.0f + expf(-g4[0]));
    float fg = 1.0f / (1.0f + expf(-g4[1]));
    float gg = tanhf(g4[2]);
    float og = 1.0f / (1.0f + expf(-g4[3]));
    float c = fg * cbuf[b * H + tid] + ig * gg;
    cbuf[b * H + tid] = c;
    float h = og * tanhf(c);
    hl[b * H + tid] = h;
    hn[tid] = h;
    __syncthreads();

    if (tid < 2) {
        float acc = bpos[tid];
        const float* wr = Wpos + tid * H;
        for (int k = 0; k < H; k++) acc += wr[k] * hn[k];
        float lp = pos[b * 2 + tid];
        pos[b * 2 + tid] = acc + lp;      // curr_pos carried
        traj[b * 2 + tid] = acc;          // pred_traj output = rel_pos
        float d = acc - gt[b * 2 + tid];
        atomicAdd(loss, d * d * (1.0f / 1024.0f));  // mean over (512,2)
    }
}

// ---------------------------------------------------------------- pool net (per group g, target i)
__global__ __launch_bounds__(256) void pool_kernel(
    const float* __restrict__ hl, const float* __restrict__ pos,
    const float* __restrict__ Wp, const float* __restrict__ bp,
    const float* __restrict__ W1, const float* __restrict__ b1,
    const float* __restrict__ W2, const float* __restrict__ b2,
    float* __restrict__ pool_h)
{
    int g = blockIdx.x, i = blockIdx.y, tid = threadIdx.x;
    // 64KB union: phase1 uses F[32][192] (feats), phase2 uses X1[32][512]
    __shared__ __align__(16) float sbuf[GSZ * PRE];

    float pix = pos[(g * GSZ + i) * 2 + 0];
    float piy = pos[(g * GSZ + i) * 2 + 1];

    // fill feats F[j][0:64]=emb(rel pos), F[j][64:192]=h_j
    for (int idx = tid; idx < GSZ * 192; idx += 256) {
        int j = idx / 192, k = idx - j * 192;
        float v;
        if (k < E) {
            float rx = pos[(g * GSZ + j) * 2 + 0] - pix;
            float ry = pos[(g * GSZ + j) * 2 + 1] - piy;
            v = bp[k] + Wp[k * 2 + 0] * rx + Wp[k * 2 + 1] * ry;
        } else {
            v = hl[(g * GSZ + j) * H + (k - E)];
        }
        sbuf[j * 192 + k] = v;
    }
    __syncthreads();

    // phase 1: x1[j][p] = relu(F[j] . W1[p] + b1[p]); thread owns p0=tid, p1=tid+256
    float a0[GSZ], a1[GSZ];
#pragma unroll
    for (int j = 0; j < GSZ; j++) { a0[j] = 0.0f; a1[j] = 0.0f; }
    {
        const float4* w0v = (const float4*)(W1 + tid * 192);
        const float4* w1v = (const float4*)(W1 + (tid + 256) * 192);
        for (int k4 = 0; k4 < 48; k4++) {
            float4 w0 = w0v[k4], w1 = w1v[k4];
#pragma unroll
            for (int j = 0; j < GSZ; j++) {
                float4 f = ((const float4*)(sbuf + j * 192))[k4];
                a0[j] += f.x * w0.x + f.y * w0.y + f.z * w0.z + f.w * w0.w;
                a1[j] += f.x * w1.x + f.y * w1.y + f.z * w1.z + f.w * w1.w;
            }
        }
    }
    float bb0 = b1[tid], bb1 = b1[tid + 256];
    __syncthreads();   // everyone done reading F before overwrite
#pragma unroll
    for (int j = 0; j < GSZ; j++) {
        sbuf[j * PRE + tid]       = fmaxf(a0[j] + bb0, 0.0f);
        sbuf[j * PRE + tid + 256] = fmaxf(a1[j] + bb1, 0.0f);
    }
    __syncthreads();

    // phase 2: x2[j][q] = relu(x1[j] . W2[q] + b2[q]); pool = max_j  (= relu(max_j pre + b))
    for (int qp = 0; qp < 2; qp++) {
        int q0 = tid + qp * 512, q1 = q0 + 256;
        float c0[GSZ], c1[GSZ];
#pragma unroll
        for (int j = 0; j < GSZ; j++) { c0[j] = 0.0f; c1[j] = 0.0f; }
        const float4* wq0 = (const float4*)(W2 + q0 * PRE);
        const float4* wq1 = (const float4*)(W2 + q1 * PRE);
        for (int p8 = 0; p8 < 64; p8++) {
            float4 w00 = wq0[p8 * 2], w01 = wq0[p8 * 2 + 1];
            float4 w10 = wq1[p8 * 2], w11 = wq1[p8 * 2 + 1];
#pragma unroll
            for (int j = 0; j < GSZ; j++) {
                const float4* xr = (const float4*)(sbuf + j * PRE);
                float4 xa = xr[p8 * 2], xb = xr[p8 * 2 + 1];
                c0[j] += xa.x * w00.x + xa.y * w00.y + xa.z * w00.z + xa.w * w00.w
                       + xb.x * w01.x + xb.y * w01.y + xb.z * w01.z + xb.w * w01.w;
                c1[j] += xa.x * w10.x + xa.y * w10.y + xa.z * w10.z + xa.w * w10.w
                       + xb.x * w11.x + xb.y * w11.y + xb.z * w11.z + xb.w * w11.w;
            }
        }
        float m0 = c0[0], m1 = c1[0];
#pragma unroll
        for (int j = 1; j < GSZ; j++) { m0 = fmaxf(m0, c0[j]); m1 = fmaxf(m1, c1[j]); }
        pool_h[(g * GSZ + i) * BOT + q0] = fmaxf(m0 + b2[q0], 0.0f);
        pool_h[(g * GSZ + i) * BOT + q1] = fmaxf(m1 + b2[q1], 0.0f);
    }
}

// ---------------------------------------------------------------- tiled fp32 GEMM: C = relu([A1|A2] @ W^T + b)
template <int BM, int BN, int TM, int TN>
__global__ __launch_bounds__(256) void gemm_relu(
    const float* __restrict__ A1, int K1,
    const float* __restrict__ A2, int K2,
    const float* __restrict__ W, const float* __restrict__ bias,
    float* __restrict__ C, int N)
{
    const int K = K1 + K2;
    const int LDA = BM + 4;   // bank-conflict pad, keeps float4 alignment
    const int LDB = BN + 4;
    __shared__ __align__(16) float As[16 * LDA];
    __shared__ __align__(16) float Bs[16 * LDB];
    int tid = threadIdx.x;
    const int TX = BN / TN;
    int tx = tid % TX, ty = tid / TX;
    int m0 = blockIdx.y * BM, n0 = blockIdx.x * BN;

    float acc[TM][TN];
#pragma unroll
    for (int i = 0; i < TM; i++)
#pragma unroll
        for (int j = 0; j < TN; j++) acc[i][j] = 0.0f;

    for (int k0 = 0; k0 < K; k0 += 16) {
        for (int idx = tid; idx < BM * 16; idx += 256) {
            int m = idx >> 4, kk = idx & 15, k = k0 + kk;
            float v = (k < K1) ? A1[(m0 + m) * K1 + k] : A2[(m0 + m) * K2 + (k - K1)];
            As[kk * LDA + m] = v;
        }
        for (int idx = tid; idx < BN * 16; idx += 256) {
            int n = idx >> 4, kk = idx & 15;
            Bs[kk * LDB + n] = W[(n0 + n) * K + k0 + kk];
        }
        __syncthreads();
#pragma unroll
        for (int kk = 0; kk < 16; kk++) {
            float a[TM], bv[TN];
#pragma unroll
            for (int i = 0; i < TM; i++) a[i] = As[kk * LDA + ty * TM + i];
#pragma unroll
            for (int j = 0; j < TN; j++) bv[j] = Bs[kk * LDB + tx * TN + j];
#pragma unroll
            for (int i = 0; i < TM; i++)
#pragma unroll
                for (int j = 0; j < TN; j++) acc[i][j] += a[i] * bv[j];
        }
        __syncthreads();
    }
#pragma unroll
    for (int i = 0; i < TM; i++) {
        int m = m0 + ty * TM + i;
#pragma unroll
        for (int j = 0; j < TN; j++) {
            int n = n0 + tx * TN + j;
            C[m * N + n] = fmaxf(acc[i][j] + bias[n], 0.0f);
        }
    }
}

// ---------------------------------------------------------------- launch
extern "C" void kernel_launch(void* const* d_in, const int* in_sizes, int n_in,
                              void* d_out, int out_size, void* d_ws, size_t ws_size,
                              hipStream_t stream)
{
    const float* last_pos     = (const float*)d_in[0];
    const float* last_pos_rel = (const float*)d_in[1];
    const float* hh           = (const float*)d_in[2];
    const float* ch           = (const float*)d_in[3];
    const float* ptr_rel      = (const float*)d_in[4];
    // d_in[5] = seq_start_end: fixed contiguous groups of 32, unused
    const float* Wih  = (const float*)d_in[6];
    const float* Whh  = (const float*)d_in[7];
    const float* bih  = (const float*)d_in[8];
    const float* bhh  = (const float*)d_in[9];
    const float* Wse  = (const float*)d_in[10];
    const float* bse  = (const float*)d_in[11];
    const float* Wpos = (const float*)d_in[12];
    const float* bpos = (const float*)d_in[13];
    const float* Wp   = (const float*)d_in[14];
    const float* bp   = (const float*)d_in[15];
    const float* W1   = (const float*)d_in[16];
    const float* b1   = (const float*)d_in[17];
    const float* W2   = (const float*)d_in[18];
    const float* b2   = (const float*)d_in[19];
    const float* Wm1  = (const float*)d_in[20];
    const float* bm1  = (const float*)d_in[21];
    const float* Wm2  = (const float*)d_in[22];
    const float* bm2  = (const float*)d_in[23];

    float* ws     = (float*)d_ws;
    float* hbuf   = ws;                    // 512*128
    float* cbuf   = hbuf + BATCH * H;      // 512*128
    float* hl     = cbuf + BATCH * H;      // 512*128
    float* pos    = hl + BATCH * H;        // 512*2
    float* pool_h = pos + BATCH * 2;       // 512*1024
    float* dh     = pool_h + BATCH * BOT;  // 512*1024

    float* out  = (float*)d_out;
    float* loss = out + SEQ * BATCH * 2;   // element 12288

    init_kernel<<<(BATCH * H + 255) / 256, 256, 0, stream>>>(hh, ch, last_pos, hbuf, cbuf, pos, loss);

    for (int t = 0; t < SEQ; t++) {
        const float* relin = (t == 0) ? last_pos_rel : (ptr_rel + (t - 1) * BATCH * 2);
        const float* gt = ptr_rel + t * BATCH * 2;
        lstm_step<<<BATCH, 128, 0, stream>>>(relin, gt, Wse, bse, Wih, Whh, bih, bhh,
                                             Wpos, bpos, hbuf, cbuf, hl, pos,
                                             out + t * BATCH * 2, loss);
        pool_kernel<<<dim3(NG, GSZ), 256, 0, stream>>>(hl, pos, Wp, bp, W1, b1, W2, b2, pool_h);
        gemm_relu<64, 64, 4, 4><<<dim3(MLPD / 64, BATCH / 64), 256, 0, stream>>>(
            hl, H, pool_h, BOT, Wm1, bm1, dh, MLPD);
        gemm_relu<32, 32, 2, 2><<<dim3(H / 32, BATCH / 32), 256, 0, stream>>>(
            dh, MLPD, (const float*)nullptr, 0, Wm2, bm2, hbuf, H);
    }
}

// Round 2
// 1356.831 us; speedup vs baseline: 5.7742x; 5.7742x over previous
//
#include <hip/hip_runtime.h>
#include <math.h>

#define BATCH 512
#define NG 16
#define GSZ 32
#define H 128
#define E 64
#define PRE 512
#define BOT 1024
#define MLPD 1024
#define SEQ 12
#define AK 1152   // Abf row length = H + BOT

typedef __attribute__((ext_vector_type(8))) short bf16x8;
typedef __attribute__((ext_vector_type(4))) float f32x4;

__device__ __forceinline__ unsigned short f2bf(float f) {
    unsigned u = __float_as_uint(f);
    u += 0x7FFF + ((u >> 16) & 1);   // round-to-nearest-even
    return (unsigned short)(u >> 16);
}

#define GLB(p) ((const __attribute__((address_space(1))) unsigned int*)(p))
#define LDS(p) ((__attribute__((address_space(3))) unsigned int*)(p))

// ---------------------------------------------------------------- init
__global__ void init_kernel(const float* __restrict__ hh, const float* __restrict__ ch,
                            const float* __restrict__ last_pos,
                            float* __restrict__ hbuf, float* __restrict__ cbuf,
                            float* __restrict__ pos, float* __restrict__ loss) {
    int idx = blockIdx.x * blockDim.x + threadIdx.x;
    if (idx < BATCH * H) { hbuf[idx] = hh[idx]; cbuf[idx] = ch[idx]; }
    if (idx < BATCH * 2) { pos[idx] = last_pos[idx]; }
    if (idx == 0) *loss = 0.0f;
}

// ---------------------------------------------------------------- weight prep
// dst[r][c] = bf16(src[r*stride + off + c])
__global__ void cvt_kernel(const float* __restrict__ src, unsigned short* __restrict__ dst,
                           int cols, int stride, int off) {
    int r = blockIdx.y, c = blockIdx.x * 256 + threadIdx.x;
    if (c < cols) dst[(size_t)r * cols + c] = f2bf(src[(size_t)r * stride + off + c]);
}

// Wc = W1e @ Wp (512x2), biash = b1 + W1e @ bp   (GEMM1 collapse)
__global__ void wc_kernel(const float* __restrict__ W1, const float* __restrict__ Wp,
                          const float* __restrict__ bp, const float* __restrict__ b1,
                          float* __restrict__ Wcx, float* __restrict__ Wcy,
                          float* __restrict__ biash) {
    int p = blockIdx.x * 256 + threadIdx.x;
    float sx = 0.f, sy = 0.f, sb = 0.f;
#pragma unroll 8
    for (int e = 0; e < E; ++e) {
        float w = W1[p * 192 + e];
        sx += w * Wp[e * 2 + 0];
        sy += w * Wp[e * 2 + 1];
        sb += w * bp[e];
    }
    Wcx[p] = sx; Wcy[p] = sy; biash[p] = b1[p] + sb;
}

// ---------------------------------------------------------------- LSTM cell (+emb, +rel_pos, +loss)
__global__ __launch_bounds__(128) void lstm_step(
    const float* __restrict__ relin, const float* __restrict__ gt,
    const float* __restrict__ Wse, const float* __restrict__ bse,
    const float* __restrict__ Wih, const float* __restrict__ Whh,
    const float* __restrict__ bih, const float* __restrict__ bhh,
    const float* __restrict__ Wpos, const float* __restrict__ bpos,
    float* __restrict__ hbuf, float* __restrict__ cbuf,
    unsigned short* __restrict__ Abf,
    float* __restrict__ pos, float* __restrict__ traj, float* __restrict__ loss)
{
    int b = blockIdx.x, tid = threadIdx.x;
    __shared__ __align__(16) float xe[E];
    __shared__ __align__(16) float hp[H];
    __shared__ __align__(16) float hn[H];
    if (tid < E) {
        float rx = relin[b * 2 + 0], ry = relin[b * 2 + 1];
        xe[tid] = bse[tid] + Wse[tid * 2 + 0] * rx + Wse[tid * 2 + 1] * ry;
    }
    hp[tid] = hbuf[b * H + tid];
    __syncthreads();

    float g4[4];
    const float4* xev = (const float4*)xe;
    const float4* hpv = (const float4*)hp;
#pragma unroll
    for (int q = 0; q < 4; q++) {
        int row = q * H + tid;
        float acc = bih[row] + bhh[row];
        const float4* wi = (const float4*)(Wih + row * E);
#pragma unroll 4
        for (int k = 0; k < E / 4; k++) {
            float4 w = wi[k], x = xev[k];
            acc += w.x * x.x + w.y * x.y + w.z * x.z + w.w * x.w;
        }
        const float4* wh = (const float4*)(Whh + row * H);
#pragma unroll 4
        for (int k = 0; k < H / 4; k++) {
            float4 w = wh[k], x = hpv[k];
            acc += w.x * x.x + w.y * x.y + w.z * x.z + w.w * x.w;
        }
        g4[q] = acc;
    }
    float ig = 1.0f / (1.0f + expf(-g4[0]));
    float fg = 1.0f / (1.0f + expf(-g4[1]));
    float gg = tanhf(g4[2]);
    float og = 1.0f / (1.0f + expf(-g4[3]));
    float c = fg * cbuf[b * H + tid] + ig * gg;
    cbuf[b * H + tid] = c;
    float h = og * tanhf(c);
    Abf[(size_t)b * AK + tid] = f2bf(h);   // h goes to pool/MLP in bf16
    hn[tid] = h;
    __syncthreads();

    if (tid < 2) {
        float acc = bpos[tid];
        const float* wr = Wpos + tid * H;
        for (int k = 0; k < H; k++) acc += wr[k] * hn[k];
        float lp = pos[b * 2 + tid];
        pos[b * 2 + tid] = acc + lp;
        traj[b * 2 + tid] = acc;
        float d = acc - gt[b * 2 + tid];
        atomicAdd(loss, d * d * (1.0f / 1024.0f));
    }
}

// ---------------------------------------------------------------- x1 build: X1[(g,i,j)][p] = relu(Hpart[(g,j)][p] + rx*Wcx + ry*Wcy)
__global__ __launch_bounds__(256) void x1_build(
    const float* __restrict__ Hpartf, const float* __restrict__ pos,
    const float* __restrict__ Wcx, const float* __restrict__ Wcy,
    unsigned short* __restrict__ X1)
{
    int g = blockIdx.x >> 5, i = blockIdx.x & 31, tid = threadIdx.x;
    __shared__ float px[GSZ], py[GSZ];
    if (tid < GSZ) { px[tid] = pos[(g * GSZ + tid) * 2]; py[tid] = pos[(g * GSZ + tid) * 2 + 1]; }
    __syncthreads();
    int c0 = tid * 2;
    float wx0 = Wcx[c0], wx1 = Wcx[c0 + 1], wy0 = Wcy[c0], wy1 = Wcy[c0 + 1];
    float pix = px[i], piy = py[i];
    size_t outbase = ((size_t)(g * GSZ + i) * GSZ) * PRE + c0;
#pragma unroll 4
    for (int j = 0; j < GSZ; ++j) {
        float rx = px[j] - pix, ry = py[j] - piy;
        float2 hp = *(const float2*)&Hpartf[(size_t)(g * GSZ + j) * PRE + c0];
        float v0 = fmaxf(hp.x + rx * wx0 + ry * wy0, 0.f);
        float v1 = fmaxf(hp.y + rx * wx1 + ry * wy1, 0.f);
        ushort2 o; o.x = f2bf(v0); o.y = f2bf(v1);
        *(ushort2*)&X1[outbase + (size_t)j * PRE] = o;
    }
}

// ---------------------------------------------------------------- generic bf16 MFMA GEMM  C = A(MxK) @ B(NxK)^T
// MODE 0: Cf = acc + bias          (fp32)
// MODE 1: Cb = bf16(relu(acc+bias))
// MODE 2: Cf = relu(acc + bias)    (fp32)
template <int BM, int BN, int MODE>
__global__ __launch_bounds__(256) void gemm_mfma(
    const unsigned short* __restrict__ A, int lda,
    const unsigned short* __restrict__ B, int ldb, int K,
    const float* __restrict__ bias,
    float* __restrict__ Cf, unsigned short* __restrict__ Cb, int ldc)
{
    constexpr int MT = BM / 32, NT = BN / 32;   // 16x16 tiles per wave (waves 2x2)
    __shared__ __align__(16) unsigned short As[BM * 64];
    __shared__ __align__(16) unsigned short Bs[BN * 64];
    int tid = threadIdx.x;
    int lane = tid & 63, w = tid >> 6, wm = w >> 1, wn = w & 1;
    int quad = lane >> 4, l16 = lane & 15;
    int m0 = blockIdx.y * BM, n0 = blockIdx.x * BN;

    f32x4 acc[MT][NT];
#pragma unroll
    for (int mt = 0; mt < MT; ++mt)
#pragma unroll
        for (int nt = 0; nt < NT; ++nt) acc[mt][nt] = (f32x4)0.f;

    for (int k0 = 0; k0 < K; k0 += 64) {
#pragma unroll
        for (int it = 0; it < BM / 32; ++it) {
            int c = it * 256 + tid;
            __builtin_amdgcn_global_load_lds(
                GLB(A + (size_t)(m0 + (c >> 3)) * lda + k0 + (c & 7) * 8),
                LDS(&As[c * 8]), 16, 0, 0);
        }
#pragma unroll
        for (int it = 0; it < BN / 32; ++it) {
            int c = it * 256 + tid;
            __builtin_amdgcn_global_load_lds(
                GLB(B + (size_t)(n0 + (c >> 3)) * ldb + k0 + (c & 7) * 8),
                LDS(&Bs[c * 8]), 16, 0, 0);
        }
        __syncthreads();
#pragma unroll
        for (int ks = 0; ks < 2; ++ks) {
            bf16x8 af[MT], bfr[NT];
#pragma unroll
            for (int mt = 0; mt < MT; ++mt)
                af[mt] = *(const bf16x8*)&As[(wm * (BM / 2) + mt * 16 + l16) * 64 + ks * 32 + quad * 8];
#pragma unroll
            for (int nt = 0; nt < NT; ++nt)
                bfr[nt] = *(const bf16x8*)&Bs[(wn * (BN / 2) + nt * 16 + l16) * 64 + ks * 32 + quad * 8];
#pragma unroll
            for (int mt = 0; mt < MT; ++mt)
#pragma unroll
                for (int nt = 0; nt < NT; ++nt)
                    acc[mt][nt] = __builtin_amdgcn_mfma_f32_16x16x32_bf16(af[mt], bfr[nt], acc[mt][nt], 0, 0, 0);
        }
        __syncthreads();
    }

#pragma unroll
    for (int mt = 0; mt < MT; ++mt) {
        int rbase = m0 + wm * (BM / 2) + mt * 16 + quad * 4;
#pragma unroll
        for (int nt = 0; nt < NT; ++nt) {
            int col = n0 + wn * (BN / 2) + nt * 16 + l16;
            float bv = bias[col];
#pragma unroll
            for (int r = 0; r < 4; ++r) {
                float v = acc[mt][nt][r] + bv;
                if (MODE >= 1) v = fmaxf(v, 0.f);
                if (MODE == 1) Cb[(size_t)(rbase + r) * ldc + col] = f2bf(v);
                else           Cf[(size_t)(rbase + r) * ldc + col] = v;
            }
        }
    }
}

// ---------------------------------------------------------------- pool GEMM2 + max-over-j epilogue
// X2 = X1(16384x512) @ W2(1024x512)^T ; pool[u][n] = relu(max_j X2[u*32+j][n] + b2[n]) -> Abf[:,128+n] bf16
__global__ __launch_bounds__(256) void pool_gemm(
    const unsigned short* __restrict__ X1, const unsigned short* __restrict__ W2b,
    const float* __restrict__ b2, unsigned short* __restrict__ Abf)
{
    constexpr int BM = 128, BN = 128, MT = 4, NT = 4;
    __shared__ __align__(16) unsigned short As[BM * 64];
    __shared__ __align__(16) unsigned short Bs[BN * 64];
    __shared__ float red[4 * 128];
    int tid = threadIdx.x;
    int lane = tid & 63, w = tid >> 6, wm = w >> 1, wn = w & 1;
    int quad = lane >> 4, l16 = lane & 15;
    int m0 = blockIdx.y * BM, n0 = blockIdx.x * BN;

    f32x4 acc[MT][NT];
#pragma unroll
    for (int mt = 0; mt < MT; ++mt)
#pragma unroll
        for (int nt = 0; nt < NT; ++nt) acc[mt][nt] = (f32x4)0.f;

    for (int k0 = 0; k0 < PRE; k0 += 64) {
#pragma unroll
        for (int it = 0; it < 4; ++it) {
            int c = it * 256 + tid;
            __builtin_amdgcn_global_load_lds(
                GLB(X1 + (size_t)(m0 + (c >> 3)) * PRE + k0 + (c & 7) * 8),
                LDS(&As[c * 8]), 16, 0, 0);
        }
#pragma unroll
        for (int it = 0; it < 4; ++it) {
            int c = it * 256 + tid;
            __builtin_amdgcn_global_load_lds(
                GLB(W2b + (size_t)(n0 + (c >> 3)) * PRE + k0 + (c & 7) * 8),
                LDS(&Bs[c * 8]), 16, 0, 0);
        }
        __syncthreads();
#pragma unroll
        for (int ks = 0; ks < 2; ++ks) {
            bf16x8 af[MT], bfr[NT];
#pragma unroll
            for (int mt = 0; mt < MT; ++mt)
                af[mt] = *(const bf16x8*)&As[(wm * 64 + mt * 16 + l16) * 64 + ks * 32 + quad * 8];
#pragma unroll
            for (int nt = 0; nt < NT; ++nt)
                bfr[nt] = *(const bf16x8*)&Bs[(wn * 64 + nt * 16 + l16) * 64 + ks * 32 + quad * 8];
#pragma unroll
            for (int mt = 0; mt < MT; ++mt)
#pragma unroll
                for (int nt = 0; nt < NT; ++nt)
                    acc[mt][nt] = __builtin_amdgcn_mfma_f32_16x16x32_bf16(af[mt], bfr[nt], acc[mt][nt], 0, 0, 0);
        }
        __syncthreads();
    }

    // max over j: rows of a 32-row unit = {mt pair} x {4 quads} x {4 regs}
#pragma unroll
    for (int nt = 0; nt < NT; ++nt) {
        float u0 = -1e30f, u1 = -1e30f;
#pragma unroll
        for (int r = 0; r < 4; ++r) {
            u0 = fmaxf(u0, fmaxf(acc[0][nt][r], acc[1][nt][r]));
            u1 = fmaxf(u1, fmaxf(acc[2][nt][r], acc[3][nt][r]));
        }
        u0 = fmaxf(u0, __shfl_xor(u0, 16)); u0 = fmaxf(u0, __shfl_xor(u0, 32));
        u1 = fmaxf(u1, __shfl_xor(u1, 16)); u1 = fmaxf(u1, __shfl_xor(u1, 32));
        if (lane < 16) {
            red[(wm * 2 + 0) * 128 + wn * 64 + nt * 16 + lane] = u0;
            red[(wm * 2 + 1) * 128 + wn * 64 + nt * 16 + lane] = u1;
        }
    }
    __syncthreads();
    for (int e = tid; e < 512; e += 256) {
        int u = e >> 7, cc = e & 127;
        int gu = blockIdx.y * 4 + u;                 // batch row (g*32+i)
        float v = fmaxf(red[e] + b2[n0 + cc], 0.f);
        Abf[(size_t)gu * AK + H + n0 + cc] = f2bf(v);
    }
}

// ---------------------------------------------------------------- launch
extern "C" void kernel_launch(void* const* d_in, const int* in_sizes, int n_in,
                              void* d_out, int out_size, void* d_ws, size_t ws_size,
                              hipStream_t stream)
{
    const float* last_pos     = (const float*)d_in[0];
    const float* last_pos_rel = (const float*)d_in[1];
    const float* hh           = (const float*)d_in[2];
    const float* ch           = (const float*)d_in[3];
    const float* ptr_rel      = (const float*)d_in[4];
    const float* Wih  = (const float*)d_in[6];
    const float* Whh  = (const float*)d_in[7];
    const float* bih  = (const float*)d_in[8];
    const float* bhh  = (const float*)d_in[9];
    const float* Wse  = (const float*)d_in[10];
    const float* bse  = (const float*)d_in[11];
    const float* Wpos = (const float*)d_in[12];
    const float* bpos = (const float*)d_in[13];
    const float* Wp   = (const float*)d_in[14];
    const float* bp   = (const float*)d_in[15];
    const float* W1   = (const float*)d_in[16];
    const float* b1   = (const float*)d_in[17];
    const float* W2   = (const float*)d_in[18];
    const float* b2   = (const float*)d_in[19];
    const float* Wm1  = (const float*)d_in[20];
    const float* bm1  = (const float*)d_in[21];
    const float* Wm2  = (const float*)d_in[22];
    const float* bm2  = (const float*)d_in[23];

    // fp32 workspace region
    float* ws     = (float*)d_ws;
    float* hbuf   = ws;                       // 65536
    float* cbuf   = hbuf + BATCH * H;         // 65536
    float* pos    = cbuf + BATCH * H;         // 1024 (padded)
    float* Hpartf = pos + 1024;               // 262144
    float* Wcx    = Hpartf + BATCH * PRE;     // 512
    float* Wcy    = Wcx + PRE;                // 512
    float* biash  = Wcy + PRE;                // 512
    // bf16 (ushort) region, 16B aligned
    unsigned short* ub    = (unsigned short*)(biash + PRE);
    unsigned short* Abf   = ub;                         // 512*1152
    unsigned short* X1    = Abf + (size_t)BATCH * AK;   // 16384*512
    unsigned short* dhbf  = X1 + (size_t)16384 * PRE;   // 512*1024
    unsigned short* W2b   = dhbf + (size_t)BATCH * MLPD;
    unsigned short* Wm1b  = W2b + (size_t)BOT * PRE;
    unsigned short* Wm2b  = Wm1b + (size_t)MLPD * AK;
    unsigned short* W1hb  = Wm2b + (size_t)H * MLPD;    // 512*128

    float* out  = (float*)d_out;
    float* loss = out + SEQ * BATCH * 2;

    // ---- once per call: weight prep ----
    cvt_kernel<<<dim3(2, BOT), 256, 0, stream>>>(W2, W2b, PRE, PRE, 0);
    cvt_kernel<<<dim3(5, MLPD), 256, 0, stream>>>(Wm1, Wm1b, AK, AK, 0);
    cvt_kernel<<<dim3(4, H), 256, 0, stream>>>(Wm2, Wm2b, MLPD, MLPD, 0);
    cvt_kernel<<<dim3(1, PRE), 256, 0, stream>>>(W1, W1hb, H, 192, E);
    wc_kernel<<<2, 256, 0, stream>>>(W1, Wp, bp, b1, Wcx, Wcy, biash);
    init_kernel<<<(BATCH * H + 255) / 256, 256, 0, stream>>>(hh, ch, last_pos, hbuf, cbuf, pos, loss);

    for (int t = 0; t < SEQ; t++) {
        const float* relin = (t == 0) ? last_pos_rel : (ptr_rel + (t - 1) * BATCH * 2);
        const float* gt = ptr_rel + t * BATCH * 2;
        lstm_step<<<BATCH, 128, 0, stream>>>(relin, gt, Wse, bse, Wih, Whh, bih, bhh,
                                             Wpos, bpos, hbuf, cbuf, Abf, pos,
                                             out + t * BATCH * 2, loss);
        // Hpart = h @ W1h^T + (b1 + W1e@bp)   [512x512, K=128]
        gemm_mfma<64, 64, 0><<<dim3(PRE / 64, BATCH / 64), 256, 0, stream>>>(
            Abf, AK, W1hb, H, H, biash, Hpartf, nullptr, PRE);
        x1_build<<<NG * GSZ, 256, 0, stream>>>(Hpartf, pos, Wcx, Wcy, X1);
        // X2 + max_j -> Abf[:,128:]   [16384x1024, K=512]
        pool_gemm<<<dim3(BOT / 128, 16384 / 128), 256, 0, stream>>>(X1, W2b, b2, Abf);
        // dh = relu([h|pool] @ Wm1^T + bm1)   [512x1024, K=1152] -> bf16
        gemm_mfma<64, 64, 1><<<dim3(MLPD / 64, BATCH / 64), 256, 0, stream>>>(
            Abf, AK, Wm1b, AK, AK, bm1, nullptr, dhbf, MLPD);
        // h = relu(dh @ Wm2^T + bm2)   [512x128, K=1024] -> fp32 hbuf
        gemm_mfma<64, 64, 2><<<dim3(H / 64, BATCH / 64), 256, 0, stream>>>(
            dhbf, MLPD, Wm2b, MLPD, MLPD, bm2, hbuf, nullptr, H);
    }
}